// Round 8
// baseline (78.459 us; speedup 1.0000x reference)
//
#include <hip/hip_runtime.h>

#define NN   640
#define NW   20    // used bitmask words per node
#define NWP  24    // padded row stride (96 B -> every row 16B-aligned)
#define H    64
#define MAXD 96    // degree cap; deg ~ Binomial(1279,.0187), mean 23.9

// Single kernel, 640 blocks x 256 threads. __launch_bounds__(256,4) caps VGPR
// at 128 -> >=4 blocks/CU -> 1024 resident slots >= 640 blocks: the software
// grid barrier cannot deadlock (all blocks co-resident by construction).
//
// Phase A: edge scatter via global atomicOr (thread g owns edge g);
//          wave0/1: xa = x@W1a, xc = x@W0a for node bid;
//          wave2 (bid<64): Wf row = W1b[bid,:]@W0a; wave3 (bid==64): bf = b1b@W0a.
// Barrier: arrival counter in ws (zeroed each launch by hipMemsetAsync).
// Phase C: per-node ego computation (round-6 structure, 4 waves).
__global__ __launch_bounds__(256, 4) void rnp_one(
    const int* __restrict__ ei, int E,
    const float* __restrict__ x,
    const float* __restrict__ W1a, const float* __restrict__ b1a,
    const float* __restrict__ W1b, const float* __restrict__ b1b,
    const float* __restrict__ W0a, const float* __restrict__ b0a,
    const float* __restrict__ W0b, const float* __restrict__ b0b,
    unsigned* __restrict__ bits, unsigned* __restrict__ ctr,
    float* __restrict__ xa, float* __restrict__ xc,
    float* __restrict__ Wf, float* __restrict__ bf,
    float* __restrict__ out)
{
    __shared__ __align__(16) unsigned rowv[NW];
    __shared__ float hpart[4][H];
    __shared__ float hshare[H];
    __shared__ unsigned short ulist[MAXD];
    __shared__ int s_deg;

    const int bid = blockIdx.x, t = threadIdx.x;
    const int lane = t & 63, wave = t >> 6;

    // ---------------- Phase A ----------------
    {
        const int g = bid * 256 + t;               // blocks 0..59 cover all edges
        if (g < E) {
            int a = ei[g], b = ei[g + E];
            if (a != b) atomicOr(&bits[a * NWP + (b >> 5)], 1u << (b & 31));
        }
    }
    if (wave < 2) {                                // xa (wave 0) / xc (wave 1) for node bid
        const float* W = wave ? W0a : W1a;
        const float xv = x[bid * H + lane];
        float a0 = 0, a1 = 0, a2 = 0, a3 = 0;
        #pragma unroll
        for (int k = 0; k < H; k += 4) {
            a0 += __shfl(xv, k, 64)     * W[k * H + lane];
            a1 += __shfl(xv, k + 1, 64) * W[(k + 1) * H + lane];
            a2 += __shfl(xv, k + 2, 64) * W[(k + 2) * H + lane];
            a3 += __shfl(xv, k + 3, 64) * W[(k + 3) * H + lane];
        }
        float r = (a0 + a1) + (a2 + a3);
        if (wave) xc[bid * H + lane] = r; else xa[bid * H + lane] = r;
    } else if (wave == 2 && bid < 64) {            // Wf row bid = W1b[bid,:] @ W0a
        const float wv = W1b[bid * 65 + lane];
        float a0 = 0, a1 = 0, a2 = 0, a3 = 0;
        #pragma unroll
        for (int e = 0; e < 64; e += 4) {
            a0 += __shfl(wv, e, 64)     * W0a[e * H + lane];
            a1 += __shfl(wv, e + 1, 64) * W0a[(e + 1) * H + lane];
            a2 += __shfl(wv, e + 2, 64) * W0a[(e + 2) * H + lane];
            a3 += __shfl(wv, e + 3, 64) * W0a[(e + 3) * H + lane];
        }
        Wf[bid * H + lane] = (a0 + a1) + (a2 + a3)
                           + W1b[bid * 65 + 64] * W0a[64 * H + lane];
    } else if (wave == 3 && bid == 64) {           // bf = b1b @ W0a
        const float bv = b1b[lane];
        float a0 = 0, a1 = 0, a2 = 0, a3 = 0;
        #pragma unroll
        for (int e = 0; e < 64; e += 4) {
            a0 += __shfl(bv, e, 64)     * W0a[e * H + lane];
            a1 += __shfl(bv, e + 1, 64) * W0a[(e + 1) * H + lane];
            a2 += __shfl(bv, e + 2, 64) * W0a[(e + 2) * H + lane];
            a3 += __shfl(bv, e + 3, 64) * W0a[(e + 3) * H + lane];
        }
        bf[lane] = (a0 + a1) + (a2 + a3) + b1b[64] * W0a[64 * H + lane];
    }

    // ---------------- grid barrier (device-scope) ----------------
    __syncthreads();                               // vmcnt(0) drain of this block's stores
    if (t == 0) {
        __threadfence();                           // release: write back to coherent point
        atomicAdd(ctr, 1u);
        while (atomicAdd(ctr, 0u) < (unsigned)NN)
            __builtin_amdgcn_s_sleep(2);
        __threadfence();                           // acquire: invalidate stale cache
    }
    __syncthreads();

    // ---------------- Phase C: per-node ego computation ----------------
    const int v = bid;

    if (t < NW) rowv[t] = bits[v * NWP + t];
    __syncthreads();

    if (wave == 0 && lane < NW) {                  // neighbor enumeration
        int off = 0;
        for (int i = 0; i < lane; ++i) off += __popc(rowv[i]);
        unsigned c = rowv[lane];
        while (c) {
            int b = __ffs(c) - 1; c &= c - 1;
            if (off < MAXD) ulist[off] = (unsigned short)(lane * 32 + b);
            ++off;
        }
        if (lane == NW - 1) s_deg = (off < MAXD) ? off : MAXD;
    }
    __syncthreads();
    const int deg = s_deg;

    const float r64 = W1a[64 * H + lane];
    const float k0  = b1a[lane] + r64;             // b1a + 1*W1a[64]
    const float k1  = r64 + W1a[65 * H + lane];    // per-cnt term

    const uint4* rv4 = (const uint4*)rowv;
    const uint4 r0 = rv4[0], r1 = rv4[1], r2 = rv4[2], r3 = rv4[3], r4 = rv4[4];

    float hacc = 0.f;
    for (int p = wave; p < deg; p += 4) {
        const int u = __builtin_amdgcn_readfirstlane((int)ulist[p]);
        const uint4* bu = (const uint4*)(bits + u * NWP);   // 16B-aligned rows
        const uint4 q0 = bu[0], q1 = bu[1], q2 = bu[2], q3 = bu[3], q4 = bu[4];
        unsigned cw[NW] = {
            r0.x & q0.x, r0.y & q0.y, r0.z & q0.z, r0.w & q0.w,
            r1.x & q1.x, r1.y & q1.y, r1.z & q1.z, r1.w & q1.w,
            r2.x & q2.x, r2.y & q2.y, r2.z & q2.z, r2.w & q2.w,
            r3.x & q3.x, r3.y & q3.y, r3.z & q3.z, r3.w & q3.w,
            r4.x & q4.x, r4.y & q4.y, r4.z & q4.z, r4.w & q4.w };
        int cnt = 0;
        #pragma unroll
        for (int j = 0; j < NW; ++j) cnt += __popc(cw[j]);
        float xs = 0.f;
        #pragma unroll
        for (int j = 0; j < NW; ++j) {
            unsigned c = cw[j];
            while (c) {
                int b = __ffs(c) - 1; c &= c - 1;
                xs += xa[(j * 32 + b) * H + lane];   // xa of common neighbor
            }
        }
        float h = xa[u * H + lane] + xs + k0 + (float)cnt * k1;
        hacc += fmaxf(h, 0.f);                       // ReLU then accumulate
    }
    hpart[wave][lane] = hacc;                        // deterministic partials
    __syncthreads();

    // tail: h = relu(xc_v + hsum@Wf + deg*bf + b0a); out = h@W0b + b0b
    if (wave == 0) {
        float hs = 0.f;
        #pragma unroll
        for (int w = 0; w < 4; ++w) hs += hpart[w][lane];
        hshare[lane] = hs;
    }
    __syncthreads();
    {
        float s = 0.f;                               // wave w covers d in [16w, 16w+16)
        #pragma unroll
        for (int i = 0; i < 16; ++i) {
            const int d = wave * 16 + i;
            s += hshare[d] * Wf[d * H + lane];
        }
        hpart[wave][lane] = s;
    }
    __syncthreads();
    if (wave == 0) {
        float s = 0.f;
        #pragma unroll
        for (int w = 0; w < 4; ++w) s += hpart[w][lane];
        float hh = xc[v * H + lane] + (float)deg * bf[lane] + b0a[lane] + s;
        hshare[lane] = fmaxf(hh, 0.f);
    }
    __syncthreads();
    {
        float s = 0.f;
        #pragma unroll
        for (int i = 0; i < 16; ++i) {
            const int d = wave * 16 + i;
            s += hshare[d] * W0b[d * H + lane];
        }
        hpart[wave][lane] = s;
    }
    __syncthreads();
    if (wave == 0) {
        float s = 0.f;
        #pragma unroll
        for (int w = 0; w < 4; ++w) s += hpart[w][lane];
        out[v * H + lane] = b0b[lane] + s;
    }
}

extern "C" void kernel_launch(void* const* d_in, const int* in_sizes, int n_in,
                              void* d_out, int out_size, void* d_ws, size_t ws_size,
                              hipStream_t stream) {
    const float* x   = (const float*)d_in[0];
    const float* W1a = (const float*)d_in[1];
    const float* b1a = (const float*)d_in[2];
    const float* W1b = (const float*)d_in[3];
    const float* b1b = (const float*)d_in[4];
    const float* W0a = (const float*)d_in[5];
    const float* b0a = (const float*)d_in[6];
    const float* W0b = (const float*)d_in[7];
    const float* b0b = (const float*)d_in[8];
    const int*   ei  = (const int*)d_in[9];
    const int    E   = in_sizes[9] / 2;

    char* ws = (char*)d_ws;
    unsigned* bits = (unsigned*)(ws);                   // 640*24*4 = 61440 B
    unsigned* ctr  = (unsigned*)(ws + 61440);           // 4 B barrier counter
    float*    xa   = (float*)(ws + 61504);              // 163840 B
    float*    xc   = (float*)(ws + 61504 + 163840);     // 163840 B
    float*    Wf   = (float*)(ws + 61504 + 2 * 163840); // 16384 B
    float*    bf   = (float*)(ws + 61504 + 2 * 163840 + 16384);

    hipMemsetAsync(ws, 0, 61504, stream);               // zero bits + ctr each launch
    rnp_one<<<NN, 256, 0, stream>>>(ei, E, x, W1a, b1a, W1b, b1b,
                                    W0a, b0a, W0b, b0b,
                                    bits, ctr, xa, xc, Wf, bf, (float*)d_out);
}

// Round 9
// 24.537 us; speedup vs baseline: 3.1976x; 3.1976x over previous
//
#include <hip/hip_runtime.h>

#define NN   640
#define NW   20    // used bitmask words per node
#define NWP  24    // padded row stride (96 B -> every row 16B-aligned)
#define H    64
#define MAXD 96    // degree cap; deg ~ Binomial(1279,.0187), mean 23.9

// ---------------- K1: prep (round-6 verbatim — measured best) ----------------
__global__ __launch_bounds__(512) void prep(
    const int* __restrict__ ei, int E,
    const float* __restrict__ x,
    const float* __restrict__ W1a, const float* __restrict__ W0a,
    const float* __restrict__ W1b, const float* __restrict__ b1b,
    unsigned* __restrict__ bits, float* __restrict__ xa, float* __restrict__ xc,
    float* __restrict__ Wf, float* __restrict__ bf)
{
    const int t = threadIdx.x, lane = t & 63, wave = t >> 6, bid = blockIdx.x;

    if (bid < 320) {
        __shared__ unsigned sb[2 * NW];
        if (t < 2 * NW) sb[t] = 0u;
        __syncthreads();
        for (int k = t; k < E; k += 512) {
            int a = ei[k];
            if ((a >> 1) == bid) {
                int b = ei[k + E];
                if (b != a) atomicOr(&sb[(a & 1) * NW + (b >> 5)], 1u << (b & 31));
            }
        }
        __syncthreads();
        if (t < 2 * NW) bits[(bid * 2 + t / NW) * NWP + (t % NW)] = sb[t];

        if (wave < 4) {                       // waves 0,1: xa; waves 2,3: xc
            const int v = bid * 2 + (wave & 1);
            const float* W = (wave < 2) ? W1a : W0a;
            const float xv = x[v * H + lane];
            float a0 = 0, a1 = 0, a2 = 0, a3 = 0;
            #pragma unroll
            for (int k = 0; k < H; k += 4) {
                a0 += __shfl(xv, k, 64)     * W[k * H + lane];
                a1 += __shfl(xv, k + 1, 64) * W[(k + 1) * H + lane];
                a2 += __shfl(xv, k + 2, 64) * W[(k + 2) * H + lane];
                a3 += __shfl(xv, k + 3, 64) * W[(k + 3) * H + lane];
            }
            float r = (a0 + a1) + (a2 + a3);
            if (wave < 2) xa[v * H + lane] = r; else xc[v * H + lane] = r;
        }
    } else if (bid < 328) {
        const int d = (bid - 320) * 8 + wave;
        const float wv = W1b[d * 65 + lane];          // lane e holds W1b[d][e]
        float a0 = 0, a1 = 0, a2 = 0, a3 = 0;
        #pragma unroll
        for (int e = 0; e < 64; e += 4) {
            a0 += __shfl(wv, e, 64)     * W0a[e * H + lane];
            a1 += __shfl(wv, e + 1, 64) * W0a[(e + 1) * H + lane];
            a2 += __shfl(wv, e + 2, 64) * W0a[(e + 2) * H + lane];
            a3 += __shfl(wv, e + 3, 64) * W0a[(e + 3) * H + lane];
        }
        Wf[d * H + lane] = (a0 + a1) + (a2 + a3) + W1b[d * 65 + 64] * W0a[64 * H + lane];
    } else if (wave == 0) {
        const float bv = b1b[lane];
        float a0 = 0, a1 = 0, a2 = 0, a3 = 0;
        #pragma unroll
        for (int e = 0; e < 64; e += 4) {
            a0 += __shfl(bv, e, 64)     * W0a[e * H + lane];
            a1 += __shfl(bv, e + 1, 64) * W0a[(e + 1) * H + lane];
            a2 += __shfl(bv, e + 2, 64) * W0a[(e + 2) * H + lane];
            a3 += __shfl(bv, e + 3, 64) * W0a[(e + 3) * H + lane];
        }
        bf[lane] = (a0 + a1) + (a2 + a3) + b1b[64] * W0a[64 * H + lane];
    }
}

// ---------------- K2: fused per-node ego computation (new) ----------------
// block = node v; 8 waves. shfl-scan enumeration, xa rows of N(v) staged in LDS
// (S2 subset of N(v) -> all gathers hit LDS), two-buffer shfl-parallel tail.
__global__ __launch_bounds__(512, 6) void fused(
    const float* __restrict__ xa,  const float* __restrict__ xc,
    const float* __restrict__ W1a, const float* __restrict__ b1a,
    const float* __restrict__ Wf,  const float* __restrict__ bf,
    const float* __restrict__ b0a,
    const float* __restrict__ W0b, const float* __restrict__ b0b,
    const unsigned* __restrict__ bits,
    float* __restrict__ out)
{
    __shared__ __align__(16) unsigned rowv[NW];
    __shared__ float xr[MAXD][H];                 // xa rows of N(v)
    __shared__ float p1[8][H];
    __shared__ float p2[8][H];
    __shared__ unsigned short ulist[MAXD];
    __shared__ int pre[NW];
    __shared__ int s_deg;

    const int v = blockIdx.x, t = threadIdx.x;
    const int lane = t & 63, wave = t >> 6;

    if (t < NW) rowv[t] = bits[v * NWP + t];
    __syncthreads();

    // enumeration: shfl-scan prefix popcount over the 20 words
    if (wave == 0) {
        unsigned word = (lane < NW) ? rowv[lane] : 0u;
        int pc = __popc(word), scan = pc;
        #pragma unroll
        for (int off = 1; off < 32; off <<= 1) {
            int nb = __shfl_up(scan, off, 64);
            if (lane >= off) scan += nb;
        }
        int o = scan - pc;                        // exclusive prefix
        if (lane < NW) pre[lane] = o;
        unsigned c = word;
        while (c) {
            int b = __ffs(c) - 1; c &= c - 1;
            if (o < MAXD) ulist[o] = (unsigned short)(lane * 32 + b);
            ++o;
        }
        if (lane == NW - 1) s_deg = (o < MAXD) ? o : MAXD;
    }
    __syncthreads();
    const int deg = s_deg;

    // stage xa rows of N(v) into LDS (one coalesced latency round)
    for (int p = wave; p < deg; p += 8)
        xr[p][lane] = xa[ulist[p] * H + lane];

    const float r64 = W1a[64 * H + lane];
    const float k0  = b1a[lane] + r64;            // b1a + 1*W1a[64]
    const float k1  = r64 + W1a[65 * H + lane];   // per-cnt term

    unsigned rw[NW];
    #pragma unroll
    for (int j = 0; j < NW; ++j) rw[j] = rowv[j];
    __syncthreads();

    float hacc = 0.f;
    for (int p = wave; p < deg; p += 8) {
        const uint4* bu = (const uint4*)(bits + ulist[p] * NWP);  // 16B-aligned
        const uint4 q0 = bu[0], q1 = bu[1], q2 = bu[2], q3 = bu[3], q4 = bu[4];
        unsigned cw[NW] = {
            rw[0]  & q0.x, rw[1]  & q0.y, rw[2]  & q0.z, rw[3]  & q0.w,
            rw[4]  & q1.x, rw[5]  & q1.y, rw[6]  & q1.z, rw[7]  & q1.w,
            rw[8]  & q2.x, rw[9]  & q2.y, rw[10] & q2.z, rw[11] & q2.w,
            rw[12] & q3.x, rw[13] & q3.y, rw[14] & q3.z, rw[15] & q3.w,
            rw[16] & q4.x, rw[17] & q4.y, rw[18] & q4.z, rw[19] & q4.w };
        int cnt = 0;
        #pragma unroll
        for (int j = 0; j < NW; ++j) cnt += __popc(cw[j]);
        float xs = 0.f;
        #pragma unroll
        for (int j = 0; j < NW; ++j) {
            unsigned c = cw[j];
            while (c) {
                int b = __ffs(c) - 1; c &= c - 1;
                int pos = pre[j] + __popc(rw[j] & ((1u << b) - 1));
                xs += xr[pos][lane];              // common-neighbor xa from LDS
            }
        }
        float h = xr[p][lane] + xs + k0 + (float)cnt * k1;
        hacc += fmaxf(h, 0.f);                    // ReLU then accumulate
    }
    p1[wave][lane] = hacc;
    __syncthreads();

    // tail: h = relu(xc_v + hsum@Wf + deg*bf + b0a); out = h@W0b + b0b
    float hs = 0.f;
    #pragma unroll
    for (int w = 0; w < 8; ++w) hs += p1[w][lane];      // every wave: full hsum
    float s = 0.f;
    #pragma unroll
    for (int i = 0; i < 8; ++i) {
        const int d = wave * 8 + i;
        s += __shfl(hs, d, 64) * Wf[d * H + lane];
    }
    p2[wave][lane] = s;
    __syncthreads();

    float s2 = 0.f;
    #pragma unroll
    for (int w = 0; w < 8; ++w) s2 += p2[w][lane];
    const float hh = fmaxf(xc[v * H + lane] + (float)deg * bf[lane]
                           + b0a[lane] + s2, 0.f);      // full h, every wave
    float o = 0.f;
    #pragma unroll
    for (int i = 0; i < 8; ++i) {
        const int d = wave * 8 + i;
        o += __shfl(hh, d, 64) * W0b[d * H + lane];
    }
    p1[wave][lane] = o;                                  // p1 reads all done pre-sync
    __syncthreads();
    if (wave == 0) {
        float oo = b0b[lane];
        #pragma unroll
        for (int w = 0; w < 8; ++w) oo += p1[w][lane];
        out[v * H + lane] = oo;
    }
}

extern "C" void kernel_launch(void* const* d_in, const int* in_sizes, int n_in,
                              void* d_out, int out_size, void* d_ws, size_t ws_size,
                              hipStream_t stream) {
    const float* x   = (const float*)d_in[0];
    const float* W1a = (const float*)d_in[1];
    const float* b1a = (const float*)d_in[2];
    const float* W1b = (const float*)d_in[3];
    const float* b1b = (const float*)d_in[4];
    const float* W0a = (const float*)d_in[5];
    const float* b0a = (const float*)d_in[6];
    const float* W0b = (const float*)d_in[7];
    const float* b0b = (const float*)d_in[8];
    const int*   ei  = (const int*)d_in[9];
    const int    E   = in_sizes[9] / 2;

    char* ws = (char*)d_ws;
    unsigned* bits = (unsigned*)(ws);                         // 640*24*4 = 61440 B
    float*    xa   = (float*)(ws + 61440);                    // 163840 B
    float*    xc   = (float*)(ws + 61440 + 163840);           // 163840 B
    float*    Wf   = (float*)(ws + 61440 + 2 * 163840);       // 16384 B
    float*    bf   = (float*)(ws + 61440 + 2 * 163840 + 16384);

    prep<<<329, 512, 0, stream>>>(ei, E, x, W1a, W0a, W1b, b1b, bits, xa, xc, Wf, bf);
    fused<<<NN, 512, 0, stream>>>(xa, xc, W1a, b1a, Wf, bf, b0a, W0b, b0b,
                                  bits, (float*)d_out);
}